// Round 1
// baseline (20057.967 us; speedup 1.0000x reference)
//
#include <hip/hip_runtime.h>
#include <stddef.h>

#define T_STEPS 512
#define BATCH   256
#define DIN     128
#define HID     256
#define HXS     392   // hx row stride in bf16 elems: 384 + 8 pad (16B-aligned rows)
#define POLL_TIMEOUT 4096   // fast-path rounds before latching to agent-scope mirror

typedef __attribute__((ext_vector_type(8))) short  short8;   // 8 bf16 (MFMA A/B frag)
typedef __attribute__((ext_vector_type(4))) float  floatx4;  // MFMA C/D frag / float4 load
typedef __attribute__((ext_vector_type(4))) unsigned int uintx4;

__device__ __forceinline__ unsigned short f2bf(float f) {
    unsigned u = __builtin_bit_cast(unsigned, f);
    u += 0x7FFFu + ((u >> 16) & 1u);   // RNE
    return (unsigned short)(u >> 16);
}
__device__ __forceinline__ short8 pack8(floatx4 a, floatx4 b) {
    short8 r;
    r[0]=(short)f2bf(a[0]); r[1]=(short)f2bf(a[1]); r[2]=(short)f2bf(a[2]); r[3]=(short)f2bf(a[3]);
    r[4]=(short)f2bf(b[0]); r[5]=(short)f2bf(b[1]); r[6]=(short)f2bf(b[2]); r[7]=(short)f2bf(b[3]);
    return r;
}
__device__ __forceinline__ float sigmoid_f(float x) { return 1.0f / (1.0f + __expf(-x)); }
__device__ __forceinline__ float tanh_f(float x) {
    float e = __expf(-2.0f * fabsf(x));          // e in (0,1], no overflow
    float r = (1.0f - e) / (1.0f + e);
    return copysignf(r, x);
}

// One fast poll round: 64B of exchange words via sc0 loads (bypass L1, served by the
// XCD-shared L2 — members of a group sit on one XCD under round-robin placement).
// Loads + waitcnt live in ONE asm block so consumers of the outputs are data-ordered
// after the waitcnt (no compiler hoisting hazard).
__device__ __forceinline__ bool poll_l2_once(const unsigned long long* p, unsigned tag,
                                             unsigned* pay) {
    uintx4 q0, q1, q2, q3;
    asm volatile(
        "global_load_dwordx4 %0, %4, off sc0\n\t"
        "global_load_dwordx4 %1, %4, off offset:16 sc0\n\t"
        "global_load_dwordx4 %2, %4, off offset:32 sc0\n\t"
        "global_load_dwordx4 %3, %4, off offset:48 sc0\n\t"
        "s_waitcnt vmcnt(0)"
        : "=&v"(q0), "=&v"(q1), "=&v"(q2), "=&v"(q3)
        : "v"(p)
        : "memory");
    bool ok = (q0[1] == tag) & (q0[3] == tag) & (q1[1] == tag) & (q1[3] == tag)
            & (q2[1] == tag) & (q2[3] == tag) & (q3[1] == tag) & (q3[3] == tag);
    pay[0] = q0[0]; pay[1] = q0[2]; pay[2] = q1[0]; pay[3] = q1[2];
    pay[4] = q2[0]; pay[5] = q2[2]; pay[6] = q3[0]; pay[7] = q3[2];
    return ok;
}

// 256 WGs x 256 threads. WG -> (group g: 16 batch rows, member m: 16 h-cols).
// Wave w (0..3) = gate w (i,f,g,o); holds W rows [w*256+m*16, +16) x K=384 as bf16 frags.
// Exchange: self-validating u64 words (tag<<32 | 2x bf16 h), double-buffered by t&1.
//   FAST path: plain/sc0 store + sc0 poll through the XCD-shared L2 (members of a group
//   share bx%8 -> same XCD under round-robin placement; ~200cyc vs ~600cyc IC).
//   SAFETY: producers also publish an agent-scope mirror; consumers that time out latch
//   permanently onto the mirror — correct regardless of WG->XCD placement, no hang.
__global__ void __launch_bounds__(256, 2) lstm_persistent(
    const float* __restrict__ x_in,   // [T,B,DIN] fp32
    const float* __restrict__ W_ih,   // [4H,DIN]  fp32
    const float* __restrict__ W_hh,   // [4H,HID]  fp32
    const float* __restrict__ b_ih,   // [4H] fp32
    const float* __restrict__ b_hh,   // [4H] fp32
    float*               __restrict__ out,   // [T,B,HID] fp32 — write-only
    unsigned long long*  __restrict__ xch,   // fast region  [2][BATCH][HID/2] u64
    unsigned long long*  __restrict__ xmir,  // agent mirror [2][BATCH][HID/2] u64
    int fast_ok)                             // 0 if workspace too small for mirror
{
    __shared__ unsigned short hx[16][HXS];     // [batch 16][h 0..255 | x 256..383] bf16
    __shared__ float gbuf[4][16][20];          // [gate][batch][col], stride 20 dwords

    const int tid  = threadIdx.x;
    const int lane = tid & 63;
    const int wave = tid >> 6;       // gate index
    const int quad = lane >> 4;
    const int l16  = lane & 15;

    const int bx = blockIdx.x;
    const int g  = (bx & 7) * 2 + ((bx >> 3) & 1);  // group 0..15 (members share bx%16 -> same XCD)
    const int m  = bx >> 4;                         // member 0..15

    // ---- one-time: fp32 weights -> persistent bf16 B-fragments ----
    short8 wfrag[12];
    {
        const int r = wave * 256 + m * 16 + l16;
        const float* wh = W_hh + (size_t)r * HID;
        const float* wi = W_ih + (size_t)r * DIN;
#pragma unroll
        for (int kt = 0; kt < 8; ++kt) {
            floatx4 a = *(const floatx4*)(wh + kt * 32 + quad * 8);
            floatx4 b = *(const floatx4*)(wh + kt * 32 + quad * 8 + 4);
            wfrag[kt] = pack8(a, b);
        }
#pragma unroll
        for (int kt = 8; kt < 12; ++kt) {
            floatx4 a = *(const floatx4*)(wi + (kt - 8) * 32 + quad * 8);
            floatx4 b = *(const floatx4*)(wi + (kt - 8) * 32 + quad * 8 + 4);
            wfrag[kt] = pack8(a, b);
        }
    }

    const int tb = tid >> 4;   // batch row 0..15 (gate/exchange phase identity)
    const int tc = tid & 15;   // h col 0..15
    const int grow = g * 16 + tb;   // absolute batch row
    float bias[4];
#pragma unroll
    for (int gi = 0; gi < 4; ++gi) {
        int r = gi * 256 + m * 16 + tc;
        bias[gi] = b_ih[r] + b_hh[r];
    }
    float c_state = 0.0f;
    int use_fast = fast_ok;    // per-thread sticky latch

    // ---- init LDS: h^0 = 0; x for step 1 = bf16(x_in[0]) ----
#pragma unroll
    for (int j = 0; j < 16; ++j) hx[tb][tc * 16 + j] = 0;
    {
        const float* src = x_in + (size_t)grow * DIN + tc * 8;
        floatx4 a = *(const floatx4*)src;
        floatx4 b = *(const floatx4*)(src + 4);
        *(short8*)&hx[tb][256 + tc * 8] = pack8(a, b);
    }
    __syncthreads();

    for (int t = 1; t <= T_STEPS; ++t) {
        const unsigned tag = (unsigned)t;

        // ---- issue x loads for step t+1 NOW: ~900cyc HBM latency hides under
        //      MFMA + barrier + gate math instead of sitting between publish and poll ----
        floatx4 xa = {0.f, 0.f, 0.f, 0.f}, xb = {0.f, 0.f, 0.f, 0.f};
        if (t < T_STEPS) {
            const float* src = x_in + ((size_t)t * BATCH + grow) * DIN + tc * 8;
            xa = *(const floatx4*)src;
            xb = *(const floatx4*)(src + 4);
        }

        // ---- A fragments: A[m=l16][k=kt*32+quad*8+j] ----
        short8 afrag[12];
#pragma unroll
        for (int kt = 0; kt < 12; ++kt)
            afrag[kt] = *(const short8*)&hx[l16][kt * 32 + quad * 8];

        floatx4 acc0 = {0.f, 0.f, 0.f, 0.f};
        floatx4 acc1 = {0.f, 0.f, 0.f, 0.f};
#pragma unroll
        for (int kt = 0; kt < 12; kt += 2) {
            acc0 = __builtin_amdgcn_mfma_f32_16x16x32_bf16(afrag[kt],     wfrag[kt],     acc0, 0, 0, 0);
            acc1 = __builtin_amdgcn_mfma_f32_16x16x32_bf16(afrag[kt + 1], wfrag[kt + 1], acc1, 0, 0, 0);
        }
        floatx4 acc = acc0 + acc1;

        // D: row(batch) = quad*4+r, col = l16
#pragma unroll
        for (int r = 0; r < 4; ++r)
            gbuf[wave][quad * 4 + r][l16] = acc[r];
        __syncthreads();   // B1: gbuf ready; all hx reads (h + x region) done

        // ---- fused gate math (fp32) ----
        float iv = sigmoid_f(gbuf[0][tb][tc] + bias[0]);
        float fv = sigmoid_f(gbuf[1][tb][tc] + bias[1]);
        float gv = tanh_f   (gbuf[2][tb][tc] + bias[2]);
        float ov = sigmoid_f(gbuf[3][tb][tc] + bias[3]);
        c_state = fv * c_state + iv * gv;
        float hv = ov * tanh_f(c_state);

        // ---- final output: fp32, write-only, non-temporal ----
        __builtin_nontemporal_store(hv, out + ((size_t)(t - 1) * BATCH + grow) * HID + m * 16 + tc);

        if (t < T_STEPS) {
            // ---- publish fast copy immediately (group peers are waiting on it) ----
            unsigned short hu = f2bf(hv);
            unsigned short hn = (unsigned short)__shfl_xor((int)hu, 1, 64);
            unsigned long long wrd = ((unsigned long long)tag << 32)
                                   | (unsigned)hu | ((unsigned)hn << 16);
            size_t widx = (((size_t)(t & 1) * BATCH) + grow) * (HID / 2) + (m * 8 + (tc >> 1));
            if (fast_ok && (tc & 1) == 0)
                asm volatile("global_store_dwordx2 %0, %1, off sc0"
                             :: "v"(&xch[widx]), "v"(wrd) : "memory");
            __atomic_signal_fence(__ATOMIC_SEQ_CST);

            // ---- x for step t+1: data already arrived (issued at loop top) ----
            *(short8*)&hx[tb][256 + tc * 8] = pack8(xa, xb);

            // ---- consumer: own 8 contiguous words (row grow, from member tc) ----
            size_t rbase = (((size_t)(t & 1) * BATCH) + grow) * (HID / 2) + tc * 8;
            unsigned pay[8];
            bool got = false;
            if (use_fast)
                got = poll_l2_once(xch + rbase, tag, pay);   // round 0, L2 latency

            // ---- agent-scope mirror publish (always; after round 0 so its IC ack
            //      doesn't sit inside the poll's vmcnt(0)) ----
            if ((tc & 1) == 0)
                __hip_atomic_store(&xmir[widx], wrd, __ATOMIC_RELAXED, __HIP_MEMORY_SCOPE_AGENT);
            __atomic_signal_fence(__ATOMIC_SEQ_CST);

            if (use_fast && !got) {
                for (int r = 1; r < POLL_TIMEOUT; ++r) {
                    got = poll_l2_once(xch + rbase, tag, pay);
                    if (got) break;
                }
                if (!got) use_fast = 0;   // placement/semantics assumption failed: latch slow
            }
            if (!got) {
                // correct regardless of XCD placement: agent scope through IC
                for (;;) {
                    bool ok = true;
                    unsigned long long v[8];
#pragma unroll
                    for (int i = 0; i < 8; ++i) {
                        v[i] = __hip_atomic_load(&xmir[rbase + i],
                                                 __ATOMIC_RELAXED, __HIP_MEMORY_SCOPE_AGENT);
                        ok &= ((unsigned)(v[i] >> 32) == tag);
                    }
                    if (ok) {
#pragma unroll
                        for (int i = 0; i < 8; ++i) pay[i] = (unsigned)v[i];
                        break;
                    }
                }
            }

            short8 h0, h1;
#pragma unroll
            for (int i = 0; i < 4; ++i) {
                h0[2 * i]     = (short)(pay[i] & 0xFFFFu);
                h0[2 * i + 1] = (short)(pay[i] >> 16);
                h1[2 * i]     = (short)(pay[i + 4] & 0xFFFFu);
                h1[2 * i + 1] = (short)(pay[i + 4] >> 16);
            }
            *(short8*)&hx[tb][tc * 16]     = h0;
            *(short8*)&hx[tb][tc * 16 + 8] = h1;
        }
        __syncthreads();   // B4: hx (h-gather + x) ready for next step's reads; gbuf reads done
    }
}

extern "C" void kernel_launch(void* const* d_in, const int* in_sizes, int n_in,
                              void* d_out, int out_size, void* d_ws, size_t ws_size,
                              hipStream_t stream) {
    const float* x   = (const float*)d_in[0];
    const float* wih = (const float*)d_in[1];
    const float* whh = (const float*)d_in[2];
    const float* bih = (const float*)d_in[3];
    const float* bhh = (const float*)d_in[4];
    // d_ws layout: [0, 512KB) fast exchange region, [512KB, 1MB) agent-scope mirror.
    // Poison 0xAAAAAAAA never matches a tag (1..511); harness re-poisons every launch;
    // dispatch-boundary L2 flush/invalidate prevents cross-launch staleness.
    const size_t XCH_WORDS = (size_t)2 * BATCH * (HID / 2);          // 65536 u64
    const size_t XCH_BYTES = XCH_WORDS * sizeof(unsigned long long); // 512 KB
    unsigned long long* xch = (unsigned long long*)d_ws;
    int fast_ok = (ws_size >= 2 * XCH_BYTES) ? 1 : 0;
    unsigned long long* xmir = fast_ok ? (xch + XCH_WORDS) : xch;    // !fast_ok: mirror==primary

    hipLaunchKernelGGL(lstm_persistent, dim3(256), dim3(256), 0, stream,
                       x, wih, whh, bih, bhh, (float*)d_out, xch, xmir, fast_ok);
}

// Round 3
// 1427.813 us; speedup vs baseline: 14.0480x; 14.0480x over previous
//
#include <hip/hip_runtime.h>
#include <stddef.h>

#define T_STEPS 512
#define BATCH   256
#define DIN     128
#define HID     256
#define HXS     392   // hx row stride in bf16 elems: 384 + 8 pad (784B, 16B-aligned rows)
#define GBS     72    // gbuf row stride in floats

typedef __attribute__((ext_vector_type(8))) short  short8;   // 8 bf16 (MFMA A/B frag)
typedef __attribute__((ext_vector_type(4))) short  bf16x4;   // 4 bf16 (8B LDS store)
typedef __attribute__((ext_vector_type(4))) float  floatx4;  // MFMA C/D frag / float4 load
typedef __attribute__((ext_vector_type(2))) float  floatx2;

__device__ __forceinline__ unsigned short f2bf(float f) {
    unsigned u = __builtin_bit_cast(unsigned, f);
    u += 0x7FFFu + ((u >> 16) & 1u);   // RNE
    return (unsigned short)(u >> 16);
}
__device__ __forceinline__ short8 pack8(floatx4 a, floatx4 b) {
    short8 r;
    r[0]=(short)f2bf(a[0]); r[1]=(short)f2bf(a[1]); r[2]=(short)f2bf(a[2]); r[3]=(short)f2bf(a[3]);
    r[4]=(short)f2bf(b[0]); r[5]=(short)f2bf(b[1]); r[6]=(short)f2bf(b[2]); r[7]=(short)f2bf(b[3]);
    return r;
}
__device__ __forceinline__ bf16x4 pack4(floatx4 a) {
    bf16x4 r;
    r[0]=(short)f2bf(a[0]); r[1]=(short)f2bf(a[1]);
    r[2]=(short)f2bf(a[2]); r[3]=(short)f2bf(a[3]);
    return r;
}
__device__ __forceinline__ float sigmoid_f(float x) { return 1.0f / (1.0f + __expf(-x)); }
__device__ __forceinline__ float tanh_f(float x) {
    float e = __expf(-2.0f * fabsf(x));          // e in (0,1], no overflow
    float r = (1.0f - e) / (1.0f + e);
    return copysignf(r, x);
}
// fp-th foreign pair (0..95) -> global pair index (0..127), skipping own member mp
__device__ __forceinline__ int foreign_pair(int fp, int mp) {
    int j = fp >> 5, o = fp & 31;
    int mm = j + (j >= mp ? 1 : 0);
    return mm * 32 + o;
}

// 64 WGs x 512 threads. WG -> (group g = bx>>2: 16 batch rows, member mp = bx&3: 64 h-cols).
// 8 waves; wave w = (gate gw=w>>1, half=w&1) computes 2 output tiles (32 gate rows) sharing
// one A-fragment read (per-CU afrag LDS traffic == baseline). Exchange: agent-scope tagged
// u64 words (R0-proven primitives), double-buffered by t&1; 4 producers/group (was 16);
// own member's 64 cols bypass global entirely (LDS); each thread polls 3 u64 (was 8).
__global__ void __launch_bounds__(512, 2) lstm_persistent(
    const float* __restrict__ x_in,   // [T,B,DIN] fp32
    const float* __restrict__ W_ih,   // [4H,DIN]  fp32
    const float* __restrict__ W_hh,   // [4H,HID]  fp32
    const float* __restrict__ b_ih,   // [4H] fp32
    const float* __restrict__ b_hh,   // [4H] fp32
    float*               __restrict__ out,  // [T,B,HID] fp32 — write-only
    unsigned long long*  __restrict__ xch)  // [2][BATCH][HID/2] u64
{
    __shared__ unsigned short hx[16][HXS];     // [batch 16][h 0..255 | x 256..383] bf16
    __shared__ float gbuf[4][16][GBS];         // [gate][batch][member-local col 0..63]

    const int tid  = threadIdx.x;
    const int lane = tid & 63;
    const int wave = tid >> 6;       // 0..7
    const int quad = lane >> 4;
    const int l16  = lane & 15;

    const int g  = blockIdx.x >> 2;  // group 0..15
    const int mp = blockIdx.x & 3;   // member 0..3

    const int gw   = wave >> 1;      // gate 0..3
    const int half = wave & 1;       // which 32-col half of the member's 64

    // ---- one-time: fp32 weights -> persistent bf16 B-fragments (2 tiles/wave) ----
    short8 wfrag0[12], wfrag1[12];
    {
        const int r0 = gw * 256 + mp * 64 + half * 32 + l16;
        const int r1 = r0 + 16;
        const float* wh0 = W_hh + (size_t)r0 * HID;
        const float* wi0 = W_ih + (size_t)r0 * DIN;
        const float* wh1 = W_hh + (size_t)r1 * HID;
        const float* wi1 = W_ih + (size_t)r1 * DIN;
#pragma unroll
        for (int kt = 0; kt < 8; ++kt) {
            wfrag0[kt] = pack8(*(const floatx4*)(wh0 + kt * 32 + quad * 8),
                               *(const floatx4*)(wh0 + kt * 32 + quad * 8 + 4));
            wfrag1[kt] = pack8(*(const floatx4*)(wh1 + kt * 32 + quad * 8),
                               *(const floatx4*)(wh1 + kt * 32 + quad * 8 + 4));
        }
#pragma unroll
        for (int kt = 8; kt < 12; ++kt) {
            wfrag0[kt] = pack8(*(const floatx4*)(wi0 + (kt - 8) * 32 + quad * 8),
                               *(const floatx4*)(wi0 + (kt - 8) * 32 + quad * 8 + 4));
            wfrag1[kt] = pack8(*(const floatx4*)(wi1 + (kt - 8) * 32 + quad * 8),
                               *(const floatx4*)(wi1 + (kt - 8) * 32 + quad * 8 + 4));
        }
    }

    // ---- scalar/exchange identity: thread (tb, tc2) owns batch row tb, h-cols {c0, c0+1} ----
    const int tb   = tid >> 5;           // batch row 0..15
    const int tc2  = tid & 31;           // pair col 0..31 within member's 64
    const int grow = g * 16 + tb;        // absolute batch row
    const int lc   = 2 * tc2;            // member-local col
    const int c0   = mp * 64 + lc;       // absolute h col

    float bias[4][2];
#pragma unroll
    for (int q = 0; q < 4; ++q) {
        int r = q * 256 + c0;
        bias[q][0] = b_ih[r] + b_hh[r];
        bias[q][1] = b_ih[r + 1] + b_hh[r + 1];
    }
    float cs0 = 0.f, cs1 = 0.f;

    // poll targets: 3 foreign pairs per thread (t-invariant indices)
    const int gp0 = foreign_pair(tc2 * 3,     mp);
    const int gp1 = foreign_pair(tc2 * 3 + 1, mp);
    const int gp2 = foreign_pair(tc2 * 3 + 2, mp);
    unsigned long long* const xrow = xch + (size_t)grow * (HID / 2);

    // ---- init LDS: h^0 = 0; x for step 1 = bf16(x_in[0]) ----
    *(short8*)&hx[tb][tc2 * 8] = (short8){0, 0, 0, 0, 0, 0, 0, 0};
    {
        floatx4 x0 = *(const floatx4*)(x_in + (size_t)grow * DIN + tc2 * 4);
        *(bf16x4*)&hx[tb][256 + tc2 * 4] = pack4(x0);
    }
    __syncthreads();

    for (int t = 1; t <= T_STEPS; ++t) {
        const unsigned tag = (unsigned)t;

        // ---- issue x loads for step t+1 NOW: HBM latency hides under MFMA+gates ----
        floatx4 xv = {0.f, 0.f, 0.f, 0.f};
        if (t < T_STEPS)
            xv = *(const floatx4*)(x_in + ((size_t)t * BATCH + grow) * DIN + tc2 * 4);

        // ---- MFMA: one shared A-frag read feeds both weight tiles ----
        floatx4 acc0 = {0.f, 0.f, 0.f, 0.f};
        floatx4 acc1 = {0.f, 0.f, 0.f, 0.f};
#pragma unroll
        for (int kt = 0; kt < 12; ++kt) {
            short8 a = *(const short8*)&hx[l16][kt * 32 + quad * 8];
            acc0 = __builtin_amdgcn_mfma_f32_16x16x32_bf16(a, wfrag0[kt], acc0, 0, 0, 0);
            acc1 = __builtin_amdgcn_mfma_f32_16x16x32_bf16(a, wfrag1[kt], acc1, 0, 0, 0);
        }
        // D: row(batch) = quad*4+r, col = l16 (member-local col = half*32 + {0,16} + l16)
#pragma unroll
        for (int r = 0; r < 4; ++r) {
            gbuf[gw][quad * 4 + r][half * 32 + l16]      = acc0[r];
            gbuf[gw][quad * 4 + r][half * 32 + 16 + l16] = acc1[r];
        }
        __syncthreads();   // B1: gbuf ready; all hx reads (h + x region) done

        // ---- fused gate math (fp32), 2 h-cols per thread ----
        floatx2 gI = *(const floatx2*)&gbuf[0][tb][lc];
        floatx2 gF = *(const floatx2*)&gbuf[1][tb][lc];
        floatx2 gG = *(const floatx2*)&gbuf[2][tb][lc];
        floatx2 gO = *(const floatx2*)&gbuf[3][tb][lc];
        float i0 = sigmoid_f(gI[0] + bias[0][0]), i1 = sigmoid_f(gI[1] + bias[0][1]);
        float f0 = sigmoid_f(gF[0] + bias[1][0]), f1 = sigmoid_f(gF[1] + bias[1][1]);
        float g0 = tanh_f   (gG[0] + bias[2][0]), g1 = tanh_f   (gG[1] + bias[2][1]);
        float o0 = sigmoid_f(gO[0] + bias[3][0]), o1 = sigmoid_f(gO[1] + bias[3][1]);
        cs0 = f0 * cs0 + i0 * g0;
        cs1 = f1 * cs1 + i1 * g1;
        float hv0 = o0 * tanh_f(cs0);
        float hv1 = o1 * tanh_f(cs1);

        if (t < T_STEPS) {
            // ---- publish own pair ASAP (1 agent-scope u64, R0-proven primitive) ----
            unsigned pay = (unsigned)f2bf(hv0) | ((unsigned)f2bf(hv1) << 16);
            unsigned long long wrd = ((unsigned long long)tag << 32) | pay;
            unsigned long long* bp = xrow + (size_t)(t & 1) * (BATCH * (HID / 2));
            __hip_atomic_store(&bp[mp * 32 + tc2], wrd, __ATOMIC_RELAXED, __HIP_MEMORY_SCOPE_AGENT);
            __atomic_signal_fence(__ATOMIC_SEQ_CST);  // compiler-only: keep store above poll

            // ---- final output: fp32, write-only, non-temporal ----
            floatx2 ho = {hv0, hv1};
            __builtin_nontemporal_store(ho, (floatx2*)(out + ((size_t)(t - 1) * BATCH + grow) * HID + c0));

            // ---- x for step t+1 (data already in flight) + own h pair direct to LDS ----
            *(bf16x4*)&hx[tb][256 + tc2 * 4] = pack4(xv);
            *(unsigned*)&hx[tb][c0] = pay;   // own 1/4 of h never leaves the CU

            // ---- consumer: poll own row's 3 foreign pairs (vs 8 words in R0) ----
            unsigned long long v0, v1, v2;
            for (;;) {
                v0 = __hip_atomic_load(&bp[gp0], __ATOMIC_RELAXED, __HIP_MEMORY_SCOPE_AGENT);
                v1 = __hip_atomic_load(&bp[gp1], __ATOMIC_RELAXED, __HIP_MEMORY_SCOPE_AGENT);
                v2 = __hip_atomic_load(&bp[gp2], __ATOMIC_RELAXED, __HIP_MEMORY_SCOPE_AGENT);
                if (((unsigned)(v0 >> 32) == tag) & ((unsigned)(v1 >> 32) == tag)
                  & ((unsigned)(v2 >> 32) == tag)) break;
            }
            *(unsigned*)&hx[tb][2 * gp0] = (unsigned)v0;
            *(unsigned*)&hx[tb][2 * gp1] = (unsigned)v1;
            *(unsigned*)&hx[tb][2 * gp2] = (unsigned)v2;
        } else {
            floatx2 ho = {hv0, hv1};
            __builtin_nontemporal_store(ho, (floatx2*)(out + ((size_t)(t - 1) * BATCH + grow) * HID + c0));
        }
        __syncthreads();   // B4: hx (h-gather + x) ready for next step's reads; gbuf reads done
    }
}

extern "C" void kernel_launch(void* const* d_in, const int* in_sizes, int n_in,
                              void* d_out, int out_size, void* d_ws, size_t ws_size,
                              hipStream_t stream) {
    const float* x   = (const float*)d_in[0];
    const float* wih = (const float*)d_in[1];
    const float* whh = (const float*)d_in[2];
    const float* bih = (const float*)d_in[3];
    const float* bhh = (const float*)d_in[4];
    // d_ws: exchange buffer [2][256][128] u64 = 512 KB. Poison 0xAAAAAAAA never matches a
    // tag (1..511), so no init pass needed; harness re-poisons before every launch.
    unsigned long long* xch = (unsigned long long*)d_ws;

    hipLaunchKernelGGL(lstm_persistent, dim3(64), dim3(512), 0, stream,
                       x, wih, whh, bih, bhh, (float*)d_out, xch);
}